// Round 2
// baseline (511.371 us; speedup 1.0000x reference)
//
#include <hip/hip_runtime.h>

#define DIM   128
#define DMASK 127
#define PLANE (DIM * DIM)     // 16384
#define VOX   (1 << 21)       // 128^3
#define NCH   12

// Per-channel shift pairs (d,h,w) = 2*(one_hot_idx - 1), derived from the
// reference's six-point construction; verified by hand against the numpy code.
__constant__ int c_sd1[12] = { 0, 0, 0, 0, 0, 2, 2, 2, 0, 0, 0, 0};
__constant__ int c_sh1[12] = { 0,-2,-2, 0, 0, 0, 0, 0, 2, 2, 2, 2};
__constant__ int c_sw1[12] = {-2, 0, 0, 2, 2, 0, 0, 0, 0, 0, 0, 0};
__constant__ int c_sd2[12] = {-2,-2, 0,-2, 0, 0, 0, 0,-2, 0, 0, 2};
__constant__ int c_sh2[12] = { 0, 0, 0, 0,-2, 0,-2, 0, 0, 0, 0, 0};
__constant__ int c_sw2[12] = { 0, 0,-2, 0, 0,-2, 0, 2, 0,-2, 2, 0};

__device__ __forceinline__ int clamp7(int v) { return min(max(v, 0), DMASK); }

// F12: diff^2 + 5-tap W-box + 5-tap H-box, fused via LDS.
// Block = one (ch, d, h-quarter). Tile: 32 output rows + 2-halo = 36 rows.
// LDS: D2[36][128] + T1[36][128] = 36 KB (< 64 KB static limit).
__global__ __launch_bounds__(256) void f12(const float* __restrict__ img,
                                           float* __restrict__ outB) {
    int b  = blockIdx.x;            // 12 * 128 * 4 = 6144 blocks
    int ch = b >> 9;
    int d  = (b >> 2) & DMASK;
    int h0 = (b & 3) << 5;          // 0,32,64,96

    __shared__ float D2[36 * DIM];
    __shared__ float T1[36 * DIM];

    int sh1 = c_sh1[ch], sw1 = c_sw1[ch];
    int sh2 = c_sh2[ch], sw2 = c_sw2[ch];
    const float* pA = img + clamp7(d + c_sd1[ch]) * PLANE;
    const float* pB = img + clamp7(d + c_sd2[ch]) * PLANE;

    int tid = threadIdx.x;

    // phase 1: D2[r][w] for global rows hq = clamp(h0-2+r), r in [0,36)
    for (int i = tid; i < 36 * DIM; i += 256) {
        int r = i >> 7, wq = i & DMASK;
        int hq = clamp7(h0 - 2 + r);
        float a = pA[clamp7(hq + sh1) * DIM + clamp7(wq + sw1)];
        float c = pB[clamp7(hq + sh2) * DIM + clamp7(wq + sw2)];
        float df = a - c;
        D2[i] = df * df;
    }
    __syncthreads();

    // phase 2: W-box (replicate-clamped) on every row
    for (int i = tid; i < 36 * DIM; i += 256) {
        int rbase = i & ~DMASK;
        int w = i & DMASK;
        float acc = 0.0f;
#pragma unroll
        for (int dw = -2; dw <= 2; ++dw)
            acc += D2[rbase + clamp7(w + dw)];
        T1[i] = acc;
    }
    __syncthreads();

    // phase 3: H-box, write 32 output rows
    float* dst = outB + (size_t)ch * VOX + d * PLANE;
    for (int i = tid; i < 32 * DIM; i += 256) {
        int h = h0 + (i >> 7);
        int w = i & DMASK;
        float acc = 0.0f;
#pragma unroll
        for (int dh = -2; dh <= 2; ++dh) {
            int loc = clamp7(h + dh) - h0 + 2;   // in [0,36)
            acc += T1[loc * DIM + w];
        }
        dst[h * DIM + w] = acc;
    }
}

__device__ __forceinline__ void block_reduce_atomic(float v, float* target) {
    float r = v;
#pragma unroll
    for (int off = 32; off > 0; off >>= 1)
        r += __shfl_down(r, off, 64);
    __shared__ float smem[4];
    int lane = threadIdx.x & 63, wv = threadIdx.x >> 6;
    if (lane == 0) smem[wv] = r;
    __syncthreads();
    if (threadIdx.x == 0)
        atomicAdd(target, smem[0] + smem[1] + smem[2] + smem[3]);
}

// Kvar: 5-tap D-box over all 12 channels, per-voxel mind_var, reduce its sum.
__global__ __launch_bounds__(256) void kvar(const float* __restrict__ B,
                                            float* __restrict__ varsum) {
    int idx = blockIdx.x * 256 + threadIdx.x;   // voxel id
    int d  = idx >> 14;
    int hw = idx & (PLANE - 1);

    int t0 = clamp7(d - 2) * PLANE, t1 = clamp7(d - 1) * PLANE, t2 = d * PLANE,
        t3 = clamp7(d + 1) * PLANE, t4 = clamp7(d + 2) * PLANE;

    float minv = 3.4e38f, sum = 0.0f;
#pragma unroll
    for (int ch = 0; ch < NCH; ++ch) {
        const float* p = B + ((size_t)ch << 21) + hw;
        float s = p[t0] + p[t1] + p[t2] + p[t3] + p[t4];
        minv = fminf(minv, s);
        sum += s;
    }
    float v = (sum * (1.0f / 12.0f) - minv) * (1.0f / 125.0f);
    block_reduce_atomic(v, varsum);
}

// kfinal: recompute D-box for both images, clip var by global mean, exp, MSE.
__global__ __launch_bounds__(256) void kfinal(const float* __restrict__ B0,
                                              const float* __restrict__ B1,
                                              const float* __restrict__ scal,
                                              float* __restrict__ losssum) {
    int idx = blockIdx.x * 256 + threadIdx.x;
    int d  = idx >> 14;
    int hw = idx & (PLANE - 1);

    int t0 = clamp7(d - 2) * PLANE, t1 = clamp7(d - 1) * PLANE, t2 = d * PLANE,
        t3 = clamp7(d + 1) * PLANE, t4 = clamp7(d + 2) * PLANE;

    float m0 = scal[0] * (1.0f / (float)VOX);
    float m1 = scal[1] * (1.0f / (float)VOX);

    float s0[NCH], s1[NCH];
    float min0 = 3.4e38f, sum0 = 0.0f, min1 = 3.4e38f, sum1 = 0.0f;
#pragma unroll
    for (int ch = 0; ch < NCH; ++ch) {
        const float* p = B0 + ((size_t)ch << 21) + hw;
        float s = p[t0] + p[t1] + p[t2] + p[t3] + p[t4];
        s0[ch] = s; min0 = fminf(min0, s); sum0 += s;
        const float* q = B1 + ((size_t)ch << 21) + hw;
        float t = q[t0] + q[t1] + q[t2] + q[t3] + q[t4];
        s1[ch] = t; min1 = fminf(min1, t); sum1 += t;
    }
    float v0 = (sum0 * (1.0f / 12.0f) - min0) * (1.0f / 125.0f);
    float v1 = (sum1 * (1.0f / 12.0f) - min1) * (1.0f / 125.0f);
    v0 = fminf(fmaxf(v0, m0 * 0.001f), m0 * 1000.0f);
    v1 = fminf(fmaxf(v1, m1 * 0.001f), m1 * 1000.0f);
    float inv0 = (1.0f / 125.0f) / v0;
    float inv1 = (1.0f / 125.0f) / v1;

    float acc = 0.0f;
#pragma unroll
    for (int ch = 0; ch < NCH; ++ch) {
        float e0 = __expf(-(s0[ch] - min0) * inv0);
        float e1 = __expf(-(s1[ch] - min1) * inv1);
        float df = e0 - e1;
        acc += df * df;
    }
    block_reduce_atomic(acc, losssum);
}

__global__ void kzero(float* p) { if (threadIdx.x < 4) p[threadIdx.x] = 0.0f; }

__global__ void kwrite(const float* __restrict__ scal, float* __restrict__ out) {
    out[0] = scal[2] * (1.0f / (12.0f * (float)VOX));
}

// Diagnostic: if ws is too small, report its size (in MB) through d_out so the
// bench's absmax value tells us ws_size instead of crashing.
__global__ void kdiag(float* out, float ws_mb) { out[0] = ws_mb; }

extern "C" void kernel_launch(void* const* d_in, const int* in_sizes, int n_in,
                              void* d_out, int out_size, void* d_ws, size_t ws_size,
                              hipStream_t stream) {
    const float* y_true = (const float*)d_in[0];
    const float* y_pred = (const float*)d_in[1];
    float* out = (float*)d_out;

    const size_t NEED = 2ull * NCH * VOX * sizeof(float) + 64;  // ~192 MB
    if (ws_size < NEED) {
        kdiag<<<1, 1, 0, stream>>>(out, (float)(ws_size >> 20));
        return;
    }

    float* B0   = (float*)d_ws;                    // 96 MB
    float* B1   = B0 + (size_t)NCH * VOX;          // 96 MB
    float* scal = B1 + (size_t)NCH * VOX;          // [0]=varsum0 [1]=varsum1 [2]=losssum

    const int gridF12 = NCH * DIM * 4;             // 6144
    const int gridVox = VOX / 256;                 // 8192

    kzero<<<1, 64, 0, stream>>>(scal);

    f12 <<<gridF12, 256, 0, stream>>>(y_true, B0);
    kvar<<<gridVox, 256, 0, stream>>>(B0, &scal[0]);

    f12 <<<gridF12, 256, 0, stream>>>(y_pred, B1);
    kvar<<<gridVox, 256, 0, stream>>>(B1, &scal[1]);

    kfinal<<<gridVox, 256, 0, stream>>>(B0, B1, scal, &scal[2]);
    kwrite<<<1, 1, 0, stream>>>(scal, out);
}

// Round 3
// 229.177 us; speedup vs baseline: 2.2313x; 2.2313x over previous
//
#include <hip/hip_runtime.h>

#define DIM   128
#define DMASK 127
#define PLANE (DIM * DIM)     // 16384
#define VOX   (1 << 21)       // 128^3
#define NCH   12

typedef __attribute__((ext_vector_type(2))) _Float16 half2v;
typedef __attribute__((ext_vector_type(4))) _Float16 half4v;
typedef __attribute__((ext_vector_type(8))) _Float16 half8v;

// Per-channel shift pairs (d,h,w) = 2*(one_hot_idx - 1), derived from the
// reference's six-point construction.
__constant__ int c_sd1[12] = { 0, 0, 0, 0, 0, 2, 2, 2, 0, 0, 0, 0};
__constant__ int c_sh1[12] = { 0,-2,-2, 0, 0, 0, 0, 0, 2, 2, 2, 2};
__constant__ int c_sw1[12] = {-2, 0, 0, 2, 2, 0, 0, 0, 0, 0, 0, 0};
__constant__ int c_sd2[12] = {-2,-2, 0,-2, 0, 0, 0, 0,-2, 0, 0, 2};
__constant__ int c_sh2[12] = { 0, 0, 0, 0,-2, 0,-2, 0, 0, 0, 0, 0};
__constant__ int c_sw2[12] = { 0, 0,-2, 0, 0,-2, 0, 2, 0,-2, 2, 0};

__device__ __forceinline__ int clamp7(int v) { return min(max(v, 0), DMASK); }

// F12: diff^2 + 5-tap W-box + 5-tap H-box, fused via LDS; fp16 output.
// Block = one (ch, d, h-quarter). LDS: D2[36][128] + T1[36][128] = 36 KB.
__global__ __launch_bounds__(256) void f12(const float* __restrict__ img,
                                           _Float16* __restrict__ outB) {
    int b  = blockIdx.x;            // 12 * 128 * 4 = 6144 blocks
    int ch = b >> 9;
    int d  = (b >> 2) & DMASK;
    int h0 = (b & 3) << 5;          // 0,32,64,96

    __shared__ float D2[36 * DIM];
    __shared__ float T1[36 * DIM];

    int sh1 = c_sh1[ch], sw1 = c_sw1[ch];
    int sh2 = c_sh2[ch], sw2 = c_sw2[ch];
    const float* pA = img + clamp7(d + c_sd1[ch]) * PLANE;
    const float* pB = img + clamp7(d + c_sd2[ch]) * PLANE;

    int tid = threadIdx.x;

    // phase 1: diff^2 rows hq = clamp(h0-2+r), r in [0,36)
    for (int i = tid; i < 36 * DIM; i += 256) {
        int r = i >> 7, wq = i & DMASK;
        int hq = clamp7(h0 - 2 + r);
        float a = pA[clamp7(hq + sh1) * DIM + clamp7(wq + sw1)];
        float c = pB[clamp7(hq + sh2) * DIM + clamp7(wq + sw2)];
        float df = a - c;
        D2[i] = df * df;
    }
    __syncthreads();

    // phase 2: W-box (replicate-clamped)
    for (int i = tid; i < 36 * DIM; i += 256) {
        int rbase = i & ~DMASK;
        int w = i & DMASK;
        float acc = 0.0f;
#pragma unroll
        for (int dw = -2; dw <= 2; ++dw)
            acc += D2[rbase + clamp7(w + dw)];
        T1[i] = acc;
    }
    __syncthreads();

    // phase 3: H-box, write 32 output rows as half2 (4B/lane stores)
    _Float16* dst = outB + (size_t)ch * VOX + d * PLANE;
    for (int i = tid; i < 32 * 64; i += 256) {
        int h = h0 + (i >> 6);
        int wp = (i & 63) << 1;
        float a0 = 0.0f, a1 = 0.0f;
#pragma unroll
        for (int dh = -2; dh <= 2; ++dh) {
            int loc = clamp7(h + dh) - h0 + 2;   // in [0,36)
            a0 += T1[loc * DIM + wp];
            a1 += T1[loc * DIM + wp + 1];
        }
        half2v hv = { (_Float16)a0, (_Float16)a1 };
        *(half2v*)(dst + h * DIM + wp) = hv;
    }
}

__device__ __forceinline__ void block_reduce_atomic(float v, float* target) {
    float r = v;
#pragma unroll
    for (int off = 32; off > 0; off >>= 1)
        r += __shfl_down(r, off, 64);
    __shared__ float smem[4];
    int lane = threadIdx.x & 63, wv = threadIdx.x >> 6;
    if (lane == 0) smem[wv] = r;
    __syncthreads();
    if (threadIdx.x == 0)
        atomicAdd(target, smem[0] + smem[1] + smem[2] + smem[3]);
}

// Kvar: 5-tap D-box, per-voxel channel min/mean, reduce sum(var).
// 8 voxels per thread via half8 (16B) loads.
__global__ __launch_bounds__(256) void kvar(const _Float16* __restrict__ B,
                                            float* __restrict__ varsum) {
    int t   = blockIdx.x * 256 + threadIdx.x;    // 0..262143
    int idx = t << 3;
    int d   = idx >> 14;
    int hw  = idx & (PLANE - 1);                 // multiple of 8

    int q0 = (clamp7(d - 2) * PLANE + hw) >> 3;
    int q1 = (clamp7(d - 1) * PLANE + hw) >> 3;
    int q2 = (d            * PLANE + hw) >> 3;
    int q3 = (clamp7(d + 1) * PLANE + hw) >> 3;
    int q4 = (clamp7(d + 2) * PLANE + hw) >> 3;

    float mn[8], sm[8];
#pragma unroll
    for (int j = 0; j < 8; ++j) { mn[j] = 3.4e38f; sm[j] = 0.0f; }

#pragma unroll
    for (int ch = 0; ch < NCH; ++ch) {
        const half8v* p = (const half8v*)(B + ((size_t)ch << 21));
        half8v a0 = p[q0], a1 = p[q1], a2 = p[q2], a3 = p[q3], a4 = p[q4];
#pragma unroll
        for (int j = 0; j < 8; ++j) {
            float s = (float)a0[j] + (float)a1[j] + (float)a2[j]
                    + (float)a3[j] + (float)a4[j];
            mn[j] = fminf(mn[j], s);
            sm[j] += s;
        }
    }
    float acc = 0.0f;
#pragma unroll
    for (int j = 0; j < 8; ++j)
        acc += (sm[j] * (1.0f / 12.0f) - mn[j]) * (1.0f / 125.0f);
    block_reduce_atomic(acc, varsum);
}

// kfinal: recompute D-box for both images (4 voxels/thread, half4 loads),
// clip var by global mean, exp, MSE reduce.
__global__ __launch_bounds__(256) void kfinal(const _Float16* __restrict__ B0,
                                              const _Float16* __restrict__ B1,
                                              const float* __restrict__ scal,
                                              float* __restrict__ losssum) {
    int t   = blockIdx.x * 256 + threadIdx.x;    // 0..524287
    int idx = t << 2;
    int d   = idx >> 14;
    int hw  = idx & (PLANE - 1);                 // multiple of 4

    int q0 = (clamp7(d - 2) * PLANE + hw) >> 2;
    int q1 = (clamp7(d - 1) * PLANE + hw) >> 2;
    int q2 = (d            * PLANE + hw) >> 2;
    int q3 = (clamp7(d + 1) * PLANE + hw) >> 2;
    int q4 = (clamp7(d + 2) * PLANE + hw) >> 2;

    float m0 = scal[0] * (1.0f / (float)VOX);
    float m1 = scal[1] * (1.0f / (float)VOX);

    float s0[NCH][4];
    float mn0[4] = {3.4e38f, 3.4e38f, 3.4e38f, 3.4e38f};
    float sm0[4] = {0.0f, 0.0f, 0.0f, 0.0f};
#pragma unroll
    for (int ch = 0; ch < NCH; ++ch) {
        const half4v* p = (const half4v*)(B0 + ((size_t)ch << 21));
        half4v a0 = p[q0], a1 = p[q1], a2 = p[q2], a3 = p[q3], a4 = p[q4];
#pragma unroll
        for (int j = 0; j < 4; ++j) {
            float s = (float)a0[j] + (float)a1[j] + (float)a2[j]
                    + (float)a3[j] + (float)a4[j];
            s0[ch][j] = s;
            mn0[j] = fminf(mn0[j], s);
            sm0[j] += s;
        }
    }
    float inv0[4];
#pragma unroll
    for (int j = 0; j < 4; ++j) {
        float v = (sm0[j] * (1.0f / 12.0f) - mn0[j]) * (1.0f / 125.0f);
        v = fminf(fmaxf(v, m0 * 0.001f), m0 * 1000.0f);
        inv0[j] = (1.0f / 125.0f) / v;
    }
    // overwrite s0 with e0
#pragma unroll
    for (int ch = 0; ch < NCH; ++ch)
#pragma unroll
        for (int j = 0; j < 4; ++j)
            s0[ch][j] = __expf(-(s0[ch][j] - mn0[j]) * inv0[j]);

    float s1[NCH][4];
    float mn1[4] = {3.4e38f, 3.4e38f, 3.4e38f, 3.4e38f};
    float sm1[4] = {0.0f, 0.0f, 0.0f, 0.0f};
#pragma unroll
    for (int ch = 0; ch < NCH; ++ch) {
        const half4v* p = (const half4v*)(B1 + ((size_t)ch << 21));
        half4v a0 = p[q0], a1 = p[q1], a2 = p[q2], a3 = p[q3], a4 = p[q4];
#pragma unroll
        for (int j = 0; j < 4; ++j) {
            float s = (float)a0[j] + (float)a1[j] + (float)a2[j]
                    + (float)a3[j] + (float)a4[j];
            s1[ch][j] = s;
            mn1[j] = fminf(mn1[j], s);
            sm1[j] += s;
        }
    }
    float inv1[4];
#pragma unroll
    for (int j = 0; j < 4; ++j) {
        float v = (sm1[j] * (1.0f / 12.0f) - mn1[j]) * (1.0f / 125.0f);
        v = fminf(fmaxf(v, m1 * 0.001f), m1 * 1000.0f);
        inv1[j] = (1.0f / 125.0f) / v;
    }

    float acc = 0.0f;
#pragma unroll
    for (int ch = 0; ch < NCH; ++ch)
#pragma unroll
        for (int j = 0; j < 4; ++j) {
            float e1 = __expf(-(s1[ch][j] - mn1[j]) * inv1[j]);
            float df = s0[ch][j] - e1;
            acc += df * df;
        }
    block_reduce_atomic(acc, losssum);
}

__global__ void kzero(float* p) { if (threadIdx.x < 4) p[threadIdx.x] = 0.0f; }

__global__ void kwrite(const float* __restrict__ scal, float* __restrict__ out) {
    out[0] = scal[2] * (1.0f / (12.0f * (float)VOX));
}

__global__ void kdiag(float* out, float ws_mb) { out[0] = ws_mb; }

extern "C" void kernel_launch(void* const* d_in, const int* in_sizes, int n_in,
                              void* d_out, int out_size, void* d_ws, size_t ws_size,
                              hipStream_t stream) {
    const float* y_true = (const float*)d_in[0];
    const float* y_pred = (const float*)d_in[1];
    float* out = (float*)d_out;

    const size_t NEED = 2ull * NCH * VOX * sizeof(_Float16) + 64;  // ~96 MB
    if (ws_size < NEED) {
        kdiag<<<1, 1, 0, stream>>>(out, (float)(ws_size >> 20));
        return;
    }

    _Float16* B0   = (_Float16*)d_ws;                // 48 MB
    _Float16* B1   = B0 + (size_t)NCH * VOX;         // 48 MB
    float*    scal = (float*)(B1 + (size_t)NCH * VOX); // [0]=var0 [1]=var1 [2]=loss

    const int gridF12 = NCH * DIM * 4;               // 6144
    const int gridV8  = VOX / 8 / 256;               // 1024
    const int gridV4  = VOX / 4 / 256;               // 2048

    kzero<<<1, 64, 0, stream>>>(scal);

    f12 <<<gridF12, 256, 0, stream>>>(y_true, B0);
    kvar<<<gridV8, 256, 0, stream>>>(B0, &scal[0]);

    f12 <<<gridF12, 256, 0, stream>>>(y_pred, B1);
    kvar<<<gridV8, 256, 0, stream>>>(B1, &scal[1]);

    kfinal<<<gridV4, 256, 0, stream>>>(B0, B1, scal, &scal[2]);
    kwrite<<<1, 1, 0, stream>>>(scal, out);
}